// Round 7
// baseline (141.825 us; speedup 1.0000x reference)
//
#include <hip/hip_runtime.h>

#define N_RAYS 262144
#define N_SAMPLES 128

typedef float vf2 __attribute__((ext_vector_type(2)));

// One wave processes FOUR rays (software-pipelined): all global loads for all
// four rays are issued up front, so later rays' loads are in flight during
// earlier rays' scan/reduction chains. 2 consecutive samples per lane per ray.
struct RayIn {
    vf2 zv, sg, c01, c23, c45;
    float nrm;
};

__device__ __forceinline__ void process_ray(
    const int lane, const RayIn& in, const size_t rbase,
    float* __restrict__ out, float* sred6)
{
    const vf2 zv = in.zv, sg = in.sg;

    // ---- dists ----
    const float z_next = __shfl_down(zv.x, 1, 64);       // z[s0+2]
    const float dist0 = (zv.y - zv.x) * in.nrm;
    const float dist1 = ((lane & 63) == 63) ? (1e10f * in.nrm)
                                            : (z_next - zv.y) * in.nrm;

    // ---- alpha / survival ----
    const float e0 = __expf(-fmaxf(sg.x, 0.0f) * dist0);
    const float e1 = __expf(-fmaxf(sg.y, 0.0f) * dist1);
    const float alpha0 = 1.0f - e0;
    const float alpha1 = 1.0f - e1;
    const float a0 = e0 + 1e-10f;
    const float a1 = e1 + 1e-10f;

    // ---- exclusive prefix product (2/lane, 64 lanes) ----
    float scan = a0 * a1;
    #pragma unroll
    for (int off = 1; off < 64; off <<= 1) {
        const float n = __shfl_up(scan, off, 64);
        if (lane >= off) scan *= n;
    }
    float excl = __shfl_up(scan, 1, 64);
    if (lane == 0) excl = 1.0f;

    const float w0 = excl * alpha0;
    const float w1 = excl * a0 * alpha1;

    // ---- weights store (non-temporal, coalesced 512B/wave) ----
    const size_t R = N_RAYS;
    vf2 wv; wv.x = w0; wv.y = w1;
    __builtin_nontemporal_store(
        wv, reinterpret_cast<vf2*>(out + 3 * R + rbase + lane * 2));

    // ---- reductions ----
    float acc   = w0 + w1;
    float depth = w0 * zv.x     + w1 * zv.y;
    float cr    = w0 * in.c01.x + w1 * in.c23.y;
    float cg    = w0 * in.c01.y + w1 * in.c45.x;
    float cb    = w0 * in.c23.x + w1 * in.c45.y;
    #pragma unroll
    for (int off = 32; off; off >>= 1) {
        acc   += __shfl_xor(acc,   off, 64);
        depth += __shfl_xor(depth, off, 64);
        cr    += __shfl_xor(cr,    off, 64);
        cg    += __shfl_xor(cg,    off, 64);
        cb    += __shfl_xor(cb,    off, 64);
    }

    if (lane == 0) {
        sred6[0] = cr;
        sred6[1] = cg;
        sred6[2] = cb;
        sred6[3] = depth;
        sred6[4] = 1.0f / fmaxf(1e-10f, depth / acc);
        sred6[5] = acc;
    }
}

__device__ __forceinline__ RayIn load_ray(
    const int lane, const size_t rbase,
    const float* __restrict__ sigma, const float* __restrict__ colors,
    const float* __restrict__ z_vals, const float* __restrict__ rays_d,
    const int ray)
{
    RayIn r;
    const int s0 = lane * 2;
    r.zv = __builtin_nontemporal_load(
        reinterpret_cast<const vf2*>(z_vals + rbase + s0));
    r.sg = __builtin_nontemporal_load(
        reinterpret_cast<const vf2*>(sigma + rbase + s0));
    const float* cbase = colors + rbase * 3 + (size_t)s0 * 3;
    r.c01 = __builtin_nontemporal_load(reinterpret_cast<const vf2*>(cbase + 0));
    r.c23 = __builtin_nontemporal_load(reinterpret_cast<const vf2*>(cbase + 2));
    r.c45 = __builtin_nontemporal_load(reinterpret_cast<const vf2*>(cbase + 4));
    const float dx = rays_d[ray * 3 + 0];
    const float dy = rays_d[ray * 3 + 1];
    const float dz = rays_d[ray * 3 + 2];
    r.nrm = sqrtf(dx * dx + dy * dy + dz * dz);
    return r;
}

__global__ __launch_bounds__(256) void volrend_kernel(
    const float* __restrict__ sigma,
    const float* __restrict__ colors,
    const float* __restrict__ z_vals,
    const float* __restrict__ rays_d,
    float* __restrict__ out)
{
    const int wid  = threadIdx.x >> 6;   // wave in block: 0..3
    const int lane = threadIdx.x & 63;
    const int ray0 = blockIdx.x * 16 + wid * 4;  // wave handles rays 4w..4w+3

    __shared__ float sred[16][6];        // per-ray: cr,cg,cb,depth,disp,acc

    const size_t rb0 = (size_t)(ray0 + 0) * N_SAMPLES;
    const size_t rb1 = (size_t)(ray0 + 1) * N_SAMPLES;
    const size_t rb2 = (size_t)(ray0 + 2) * N_SAMPLES;
    const size_t rb3 = (size_t)(ray0 + 3) * N_SAMPLES;

    // ---- issue ALL loads for all four rays up front (max MLP) ----
    const RayIn in0 = load_ray(lane, rb0, sigma, colors, z_vals, rays_d, ray0 + 0);
    const RayIn in1 = load_ray(lane, rb1, sigma, colors, z_vals, rays_d, ray0 + 1);
    const RayIn in2 = load_ray(lane, rb2, sigma, colors, z_vals, rays_d, ray0 + 2);
    const RayIn in3 = load_ray(lane, rb3, sigma, colors, z_vals, rays_d, ray0 + 3);

    // ---- compute rays in order; later rays' loads still in flight ----
    process_ray(lane, in0, rb0, out, sred[wid * 4 + 0]);
    process_ray(lane, in1, rb1, out, sred[wid * 4 + 1]);
    process_ray(lane, in2, rb2, out, sred[wid * 4 + 2]);
    process_ray(lane, in3, rb3, out, sred[wid * 4 + 3]);

    __syncthreads();

    // ---- coalesced epilogue (16 rays per block) ----
    // out layout (flat, f32): rgb[R,3] | weights[R,128] | depth[R] | disp[R] | acc[R]
    const size_t R = N_RAYS;
    const int t = threadIdx.x;
    if (t < 48) {                       // rgb: 48 consecutive floats per block
        out[(size_t)blockIdx.x * 48 + t] = sred[t / 3][t % 3];
    } else if (t < 64) {                // depth: 16 consecutive floats
        out[131 * R + (size_t)blockIdx.x * 16 + (t - 48)] = sred[t - 48][3];
    } else if (t < 80) {                // disp
        out[132 * R + (size_t)blockIdx.x * 16 + (t - 64)] = sred[t - 64][4];
    } else if (t < 96) {                // acc
        out[133 * R + (size_t)blockIdx.x * 16 + (t - 80)] = sred[t - 80][5];
    }
}

extern "C" void kernel_launch(void* const* d_in, const int* in_sizes, int n_in,
                              void* d_out, int out_size, void* d_ws, size_t ws_size,
                              hipStream_t stream) {
    const float* sigma  = (const float*)d_in[0];
    const float* colors = (const float*)d_in[1];
    const float* z_vals = (const float*)d_in[2];
    const float* rays_d = (const float*)d_in[3];
    float* out = (float*)d_out;

    dim3 block(256);                 // 4 waves = 16 rays per block
    dim3 grid(N_RAYS / 16);          // 16384 blocks
    volrend_kernel<<<grid, block, 0, stream>>>(sigma, colors, z_vals, rays_d, out);
}

// Round 8
// 140.228 us; speedup vs baseline: 1.0114x; 1.0114x over previous
//
#include <hip/hip_runtime.h>

#define N_RAYS 262144
#define N_SAMPLES 128

typedef float vf2 __attribute__((ext_vector_type(2)));

// One wave processes TWO rays (software-pipelined): all global loads for both
// rays are issued up front, so ray B's loads are in flight during ray A's
// scan/reduction chain. 2 consecutive samples per lane per ray.
struct RayIn {
    vf2 zv, sg, c01, c23, c45;
    float nrm;
};

__device__ __forceinline__ void process_ray(
    const int lane, const RayIn& in, const size_t rbase,
    float* __restrict__ out, float* sred6)
{
    const vf2 zv = in.zv, sg = in.sg;

    // ---- dists ----
    const float z_next = __shfl_down(zv.x, 1, 64);       // z[s0+2]
    const float dist0 = (zv.y - zv.x) * in.nrm;
    const float dist1 = ((lane & 63) == 63) ? (1e10f * in.nrm)
                                            : (z_next - zv.y) * in.nrm;

    // ---- alpha / survival ----
    const float e0 = __expf(-fmaxf(sg.x, 0.0f) * dist0);
    const float e1 = __expf(-fmaxf(sg.y, 0.0f) * dist1);
    const float alpha0 = 1.0f - e0;
    const float alpha1 = 1.0f - e1;
    const float a0 = e0 + 1e-10f;
    const float a1 = e1 + 1e-10f;

    // ---- exclusive prefix product (2/lane, 64 lanes) ----
    float scan = a0 * a1;
    #pragma unroll
    for (int off = 1; off < 64; off <<= 1) {
        const float n = __shfl_up(scan, off, 64);
        if (lane >= off) scan *= n;
    }
    float excl = __shfl_up(scan, 1, 64);
    if (lane == 0) excl = 1.0f;

    const float w0 = excl * alpha0;
    const float w1 = excl * a0 * alpha1;

    // ---- weights store (non-temporal, coalesced 512B/wave) ----
    const size_t R = N_RAYS;
    vf2 wv; wv.x = w0; wv.y = w1;
    __builtin_nontemporal_store(
        wv, reinterpret_cast<vf2*>(out + 3 * R + rbase + lane * 2));

    // ---- reductions ----
    float acc   = w0 + w1;
    float depth = w0 * zv.x     + w1 * zv.y;
    float cr    = w0 * in.c01.x + w1 * in.c23.y;
    float cg    = w0 * in.c01.y + w1 * in.c45.x;
    float cb    = w0 * in.c23.x + w1 * in.c45.y;
    #pragma unroll
    for (int off = 32; off; off >>= 1) {
        acc   += __shfl_xor(acc,   off, 64);
        depth += __shfl_xor(depth, off, 64);
        cr    += __shfl_xor(cr,    off, 64);
        cg    += __shfl_xor(cg,    off, 64);
        cb    += __shfl_xor(cb,    off, 64);
    }

    if (lane == 0) {
        sred6[0] = cr;
        sred6[1] = cg;
        sred6[2] = cb;
        sred6[3] = depth;
        sred6[4] = 1.0f / fmaxf(1e-10f, depth / acc);
        sred6[5] = acc;
    }
}

__device__ __forceinline__ RayIn load_ray(
    const int lane, const size_t rbase,
    const float* __restrict__ sigma, const float* __restrict__ colors,
    const float* __restrict__ z_vals, const float* __restrict__ rays_d,
    const int ray)
{
    RayIn r;
    const int s0 = lane * 2;
    r.zv = __builtin_nontemporal_load(
        reinterpret_cast<const vf2*>(z_vals + rbase + s0));
    r.sg = __builtin_nontemporal_load(
        reinterpret_cast<const vf2*>(sigma + rbase + s0));
    const float* cbase = colors + rbase * 3 + (size_t)s0 * 3;
    r.c01 = __builtin_nontemporal_load(reinterpret_cast<const vf2*>(cbase + 0));
    r.c23 = __builtin_nontemporal_load(reinterpret_cast<const vf2*>(cbase + 2));
    r.c45 = __builtin_nontemporal_load(reinterpret_cast<const vf2*>(cbase + 4));
    const float dx = rays_d[ray * 3 + 0];
    const float dy = rays_d[ray * 3 + 1];
    const float dz = rays_d[ray * 3 + 2];
    r.nrm = sqrtf(dx * dx + dy * dy + dz * dz);
    return r;
}

__global__ __launch_bounds__(256) void volrend_kernel(
    const float* __restrict__ sigma,
    const float* __restrict__ colors,
    const float* __restrict__ z_vals,
    const float* __restrict__ rays_d,
    float* __restrict__ out)
{
    const int wid  = threadIdx.x >> 6;   // wave in block: 0..3
    const int lane = threadIdx.x & 63;
    const int rayA = blockIdx.x * 8 + wid * 2;   // wave handles rays 2w, 2w+1
    const int rayB = rayA + 1;

    __shared__ float sred[8][6];         // per-ray: cr,cg,cb,depth,disp,acc

    const size_t rbaseA = (size_t)rayA * N_SAMPLES;
    const size_t rbaseB = (size_t)rayB * N_SAMPLES;

    // ---- issue ALL loads for BOTH rays up front (max MLP) ----
    const RayIn inA = load_ray(lane, rbaseA, sigma, colors, z_vals, rays_d, rayA);
    const RayIn inB = load_ray(lane, rbaseB, sigma, colors, z_vals, rays_d, rayB);

    // ---- compute ray A while ray B's loads are in flight ----
    process_ray(lane, inA, rbaseA, out, sred[wid * 2 + 0]);
    process_ray(lane, inB, rbaseB, out, sred[wid * 2 + 1]);

    __syncthreads();

    // ---- coalesced epilogue (8 rays per block) ----
    // out layout (flat, f32): rgb[R,3] | weights[R,128] | depth[R] | disp[R] | acc[R]
    const size_t R = N_RAYS;
    const int t = threadIdx.x;
    if (t < 24) {                       // rgb: 24 consecutive floats per block
        out[(size_t)blockIdx.x * 24 + t] = sred[t / 3][t % 3];
    } else if (t < 32) {                // depth: 8 consecutive floats
        out[131 * R + (size_t)blockIdx.x * 8 + (t - 24)] = sred[t - 24][3];
    } else if (t < 40) {                // disp
        out[132 * R + (size_t)blockIdx.x * 8 + (t - 32)] = sred[t - 32][4];
    } else if (t < 48) {                // acc
        out[133 * R + (size_t)blockIdx.x * 8 + (t - 40)] = sred[t - 40][5];
    }
}

extern "C" void kernel_launch(void* const* d_in, const int* in_sizes, int n_in,
                              void* d_out, int out_size, void* d_ws, size_t ws_size,
                              hipStream_t stream) {
    const float* sigma  = (const float*)d_in[0];
    const float* colors = (const float*)d_in[1];
    const float* z_vals = (const float*)d_in[2];
    const float* rays_d = (const float*)d_in[3];
    float* out = (float*)d_out;

    dim3 block(256);                 // 4 waves = 8 rays per block
    dim3 grid(N_RAYS / 8);           // 32768 blocks
    volrend_kernel<<<grid, block, 0, stream>>>(sigma, colors, z_vals, rays_d, out);
}